// Round 4
// baseline (345.050 us; speedup 1.0000x reference)
//
#include <hip/hip_runtime.h>

#define HW 512
#define RA 0.35355339059327373f
#define RB 0.25f

typedef float fx4 __attribute__((ext_vector_type(4)));

__device__ __forceinline__ int reflect512(int v) {
    v = v < 0 ? -v : v;
    v = v > 511 ? 1022 - v : v;
    return v;
}

__device__ __forceinline__ float softt(float x) {
    return copysignf(fmaxf(fabsf(x) - 0.05f, 0.0f), x);
}

__device__ __forceinline__ void haar_quad(float a, float b, float c, float d,
                                          float& oa, float& ob, float& oc, float& od) {
    float LL = (a + b + c + d) * 0.5f;
    float LH = (a + b - c - d) * 0.5f;
    float HL = (a - b + c - d) * 0.5f;
    float HH = (a - b - c + d) * 0.5f;
    LH = softt(LH); HL = softt(HL); HH = softt(HH);
    oa = (LL + LH + HL + HH) * 0.5f;
    ob = (LL + LH - HL - HH) * 0.5f;
    oc = (LL - LH + HL - HH) * 0.5f;
    od = (LL - LH - HL + HH) * 0.5f;
}

// Packed real-DFT8 (ortho). In: x[0..7]. Out: o = [p0,p1,p2,p3,p4,q1,q2,q3]
// Full rows: P = [p0,p1,p2,p3,p4,p3,p2,p1], Q = [0,q1,q2,q3,0,-q3,-q2,-q1].
__device__ __forceinline__ void rfft8(const float* __restrict__ x, float* __restrict__ o) {
    float e0 = x[0] + x[4], d0 = x[0] - x[4];
    float e1 = x[2] + x[6], d1 = x[2] - x[6];
    float o0 = x[1] + x[5], m0 = x[1] - x[5];
    float o1 = x[3] + x[7], m1 = x[3] - x[7];
    float see = e0 + e1, dee = e0 - e1, soo = o0 + o1;
    float dd = m0 - m1, qq = m0 + m1;
    o[0] = RA * (see + soo);
    o[4] = RA * (see - soo);
    o[2] = RA * dee;
    float t0 = RA * d0, t1 = RB * dd;
    o[1] = t0 + t1;
    o[3] = t0 - t1;
    float u0 = RB * qq, u1 = RA * d1;
    o[5] = u0 + u1;            // q1
    o[6] = RA * (o0 - o1);     // q2
    o[7] = u0 - u1;            // q3
}

// Full cos butterfly: t[u] = sum_m x[m] cos(2pi um/8)/sqrt8
__device__ __forceinline__ void dft8_cos(const float* __restrict__ x, float* __restrict__ t) {
    float e0 = x[0] + x[4], d0 = x[0] - x[4];
    float e1 = x[2] + x[6];
    float o0 = x[1] + x[5], m0 = x[1] - x[5];
    float o1 = x[3] + x[7], m1 = x[3] - x[7];
    float see = e0 + e1, dee = e0 - e1, soo = o0 + o1;
    float dd = m0 - m1;
    t[0] = RA * (see + soo);
    t[4] = RA * (see - soo);
    float p2 = RA * dee;
    t[2] = p2; t[6] = p2;
    float a0 = RA * d0, a1 = RB * dd;
    t[1] = a0 + a1; t[7] = a0 + a1;
    t[3] = a0 - a1; t[5] = a0 - a1;
}

// Full sin butterfly: t[u] = sum_m x[m] sin(2pi um/8)/sqrt8
__device__ __forceinline__ void dft8_sin(const float* __restrict__ x, float* __restrict__ t) {
    float d1 = x[2] - x[6];
    float o0 = x[1] + x[5], m0 = x[1] - x[5];
    float o1 = x[3] + x[7], m1 = x[3] - x[7];
    float qq = m0 + m1;
    t[0] = 0.0f; t[4] = 0.0f;
    float q2 = RA * (o0 - o1);
    t[2] = q2; t[6] = -q2;
    float a0 = RB * qq, a1 = RA * d1;
    t[1] = a0 + a1; t[7] = -(a0 + a1);
    t[3] = a0 - a1; t[5] = -(a0 - a1);
}

__device__ __forceinline__ float nonlin(float t) {
    float ca = fabsf(t);
    t = (ca < 2.5f) ? t * (ca * 0.4f) : t;
    return fminf(fmaxf(t, -10.0f), 10.0f);
}

// In-place packed column transform on A[8][8] (rows = packed RFFT of B rows).
// Writes T[u][v] at A[u][sg(v)] where sg = {0,1,2,3,4,7,6,5}.
template <bool NL>
__device__ __forceinline__ void colpass(float A[8][8]) {
#pragma unroll
    for (int v0 = 0; v0 <= 4; v0 += 4) {   // q-columns are zero here
        float c[8], t[8];
#pragma unroll
        for (int m = 0; m < 8; ++m) c[m] = A[m][v0];
        dft8_cos(c, t);
#pragma unroll
        for (int u = 0; u < 8; ++u) A[u][v0] = NL ? nonlin(t[u]) : t[u];
    }
#pragma unroll
    for (int v = 1; v <= 3; ++v) {         // pair (v, 8-v): cv -+ sv
        float c[8], q[8], tc[8], ts[8];
#pragma unroll
        for (int m = 0; m < 8; ++m) { c[m] = A[m][v]; q[m] = A[m][4 + v]; }
        dft8_cos(c, tc);
        dft8_sin(q, ts);
#pragma unroll
        for (int u = 0; u < 8; ++u) {
            float lo = tc[u] - ts[u];      // T[u][v]
            float hi = tc[u] + ts[u];      // T[u][8-v] -> slot 4+v
            A[u][v] = NL ? nonlin(lo) : lo;
            A[u][4 + v] = NL ? nonlin(hi) : hi;
        }
    }
}

__launch_bounds__(256, 3)
__global__ void sas_fused(const float* __restrict__ in, float* __restrict__ out) {
    const int lane = threadIdx.x & 63;   // block-col 0..63
    const int wv = threadIdx.x >> 6;
    const int p = blockIdx.y;            // plane (b*3+c)
    const int by = blockIdx.x * 4 + wv;  // block-row 0..63
    const float* __restrict__ inP = in + (size_t)p * (HW * HW);
    const int cx = lane * 8;

    const float e = 0.45783336f;                  // exp(-1/1.28)
    const float inv_s = 1.0f / ((1.0f + 2.0f * e) * (1.0f + 2.0f * e));

    // ---- all 10 halo-row loads issued up front (coalesced full-row reads) ----
    fx4 va[10], vb[10];
#pragma unroll
    for (int j = 0; j < 10; ++j) {
        int gy = reflect512(by * 8 - 1 + j);
        const float* r = inP + (size_t)gy * HW + cx;
        va[j] = *(const fx4*)r;
        vb[j] = *(const fx4*)(r + 4);
    }

    // ---- streaming blur (3-row ring) + row-pass into packed A; keep B for residual ----
    float h[3][8];
    float B[8][8], A[8][8];
#pragma unroll
    for (int j = 0; j < 10; ++j) {
        float lft = __shfl_up(vb[j].w, 1);
        float rgt = __shfl_down(va[j].x, 1);
        if (lane == 0)  lft = va[j].y;
        if (lane == 63) rgt = vb[j].z;
        float x0 = lft, x1 = va[j].x, x2 = va[j].y, x3 = va[j].z, x4 = va[j].w;
        float x5 = vb[j].x, x6 = vb[j].y, x7 = vb[j].z, x8 = vb[j].w, x9 = rgt;
        float* hj = h[j % 3];
        hj[0] = e * (x0 + x2) + x1;
        hj[1] = e * (x1 + x3) + x2;
        hj[2] = e * (x2 + x4) + x3;
        hj[3] = e * (x3 + x5) + x4;
        hj[4] = e * (x4 + x6) + x5;
        hj[5] = e * (x5 + x7) + x6;
        hj[6] = e * (x6 + x8) + x7;
        hj[7] = e * (x7 + x9) + x8;
        if (j >= 2) {
            const int r = j - 2;
            const float* h0 = h[r % 3];
            const float* h1 = h[(r + 1) % 3];
            const float* h2 = h[(r + 2) % 3];
#pragma unroll
            for (int c = 0; c < 8; ++c)
                B[r][c] = (e * (h0[c] + h2[c]) + h1[c]) * inv_s;
            rfft8(B[r], A[r]);
        }
    }

    // ---- forward col pass + nonlinearity (T in A, permuted cols) ----
    colpass<true>(A);

    // ---- inverse: row pass (read with sg permutation), then col pass ----
#pragma unroll
    for (int m = 0; m < 8; ++m) {
        float x[8] = {A[m][0], A[m][1], A[m][2], A[m][3],
                      A[m][4], A[m][7], A[m][6], A[m][5]};
        rfft8(x, A[m]);
    }
    colpass<false>(A);
    // rec[u][v] now at A[u][sg(v)], sg = {0,1,2,3,4,7,6,5}

    // ---- residual + Haar refine + nontemporal coalesced stores ----
    constexpr int SG[8] = {0, 1, 2, 3, 4, 7, 6, 5};
    const int chId = (p / 3) * 6 + (p % 3);
    float* __restrict__ oI = out + ((size_t)chId << 18);
    float* __restrict__ oR = out + ((size_t)(chId + 3) << 18);
#pragma unroll
    for (int qy = 0; qy < 4; ++qy) {
        float ti[2][8], tr_[2][8];
#pragma unroll
        for (int qx = 0; qx < 4; ++qx) {
            float d00 = A[2*qy][SG[2*qx]],   d01 = A[2*qy][SG[2*qx+1]];
            float d10 = A[2*qy+1][SG[2*qx]], d11 = A[2*qy+1][SG[2*qx+1]];
            haar_quad(d00, d01, d10, d11,
                      ti[0][2*qx], ti[0][2*qx+1], ti[1][2*qx], ti[1][2*qx+1]);
            float r00 = B[2*qy][2*qx]   - d00, r01 = B[2*qy][2*qx+1]   - d01;
            float r10 = B[2*qy+1][2*qx] - d10, r11 = B[2*qy+1][2*qx+1] - d11;
            haar_quad(r00, r01, r10, r11,
                      tr_[0][2*qx], tr_[0][2*qx+1], tr_[1][2*qx], tr_[1][2*qx+1]);
        }
        size_t base = (size_t)(by * 8 + 2 * qy) * HW + cx;
        fx4 w;
        w = (fx4){ti[0][0], ti[0][1], ti[0][2], ti[0][3]};
        __builtin_nontemporal_store(w, (fx4*)&oI[base]);
        w = (fx4){ti[0][4], ti[0][5], ti[0][6], ti[0][7]};
        __builtin_nontemporal_store(w, (fx4*)&oI[base + 4]);
        w = (fx4){ti[1][0], ti[1][1], ti[1][2], ti[1][3]};
        __builtin_nontemporal_store(w, (fx4*)&oI[base + HW]);
        w = (fx4){ti[1][4], ti[1][5], ti[1][6], ti[1][7]};
        __builtin_nontemporal_store(w, (fx4*)&oI[base + HW + 4]);
        w = (fx4){tr_[0][0], tr_[0][1], tr_[0][2], tr_[0][3]};
        __builtin_nontemporal_store(w, (fx4*)&oR[base]);
        w = (fx4){tr_[0][4], tr_[0][5], tr_[0][6], tr_[0][7]};
        __builtin_nontemporal_store(w, (fx4*)&oR[base + 4]);
        w = (fx4){tr_[1][0], tr_[1][1], tr_[1][2], tr_[1][3]};
        __builtin_nontemporal_store(w, (fx4*)&oR[base + HW]);
        w = (fx4){tr_[1][4], tr_[1][5], tr_[1][6], tr_[1][7]};
        __builtin_nontemporal_store(w, (fx4*)&oR[base + HW + 4]);
    }
}

extern "C" void kernel_launch(void* const* d_in, const int* in_sizes, int n_in,
                              void* d_out, int out_size, void* d_ws, size_t ws_size,
                              hipStream_t stream) {
    const float* I = (const float*)d_in[0];
    float* out = (float*)d_out;
    dim3 grid(16, 96);   // 16 wg x 4 waves = 64 block-rows per plane; 96 planes
    sas_fused<<<grid, dim3(256), 0, stream>>>(I, out);
}

// Round 5
// 329.035 us; speedup vs baseline: 1.0487x; 1.0487x over previous
//
#include <hip/hip_runtime.h>

#define HW 512
#define RA 0.35355339059327373f
#define RB 0.25f

typedef float fx4 __attribute__((ext_vector_type(4)));

__device__ __forceinline__ int reflect512(int v) {
    v = v < 0 ? -v : v;
    v = v > 511 ? 1022 - v : v;
    return v;
}

__device__ __forceinline__ float softt(float x) {
    return copysignf(fmaxf(fabsf(x) - 0.05f, 0.0f), x);
}

__device__ __forceinline__ void haar_quad(float a, float b, float c, float d,
                                          float& oa, float& ob, float& oc, float& od) {
    float LL = (a + b + c + d) * 0.5f;
    float LH = (a + b - c - d) * 0.5f;
    float HL = (a - b + c - d) * 0.5f;
    float HH = (a - b - c + d) * 0.5f;
    LH = softt(LH); HL = softt(HL); HH = softt(HH);
    oa = (LL + LH + HL + HH) * 0.5f;
    ob = (LL + LH - HL - HH) * 0.5f;
    oc = (LL - LH + HL - HH) * 0.5f;
    od = (LL - LH - HL + HH) * 0.5f;
}

// Packed real-DFT8 (ortho). In: x[0..7]. Out: o = [p0,p1,p2,p3,p4,q1,q2,q3]
// Full rows: P = [p0,p1,p2,p3,p4,p3,p2,p1], Q = [0,q1,q2,q3,0,-q3,-q2,-q1].
__device__ __forceinline__ void rfft8(const float* __restrict__ x, float* __restrict__ o) {
    float e0 = x[0] + x[4], d0 = x[0] - x[4];
    float e1 = x[2] + x[6], d1 = x[2] - x[6];
    float o0 = x[1] + x[5], m0 = x[1] - x[5];
    float o1 = x[3] + x[7], m1 = x[3] - x[7];
    float see = e0 + e1, dee = e0 - e1, soo = o0 + o1;
    float dd = m0 - m1, qq = m0 + m1;
    o[0] = RA * (see + soo);
    o[4] = RA * (see - soo);
    o[2] = RA * dee;
    float t0 = RA * d0, t1 = RB * dd;
    o[1] = t0 + t1;
    o[3] = t0 - t1;
    float u0 = RB * qq, u1 = RA * d1;
    o[5] = u0 + u1;            // q1
    o[6] = RA * (o0 - o1);     // q2
    o[7] = u0 - u1;            // q3
}

// Full cos butterfly: t[u] = sum_m x[m] cos(2pi um/8)/sqrt8
__device__ __forceinline__ void dft8_cos(const float* __restrict__ x, float* __restrict__ t) {
    float e0 = x[0] + x[4], d0 = x[0] - x[4];
    float e1 = x[2] + x[6];
    float o0 = x[1] + x[5], m0 = x[1] - x[5];
    float o1 = x[3] + x[7], m1 = x[3] - x[7];
    float see = e0 + e1, dee = e0 - e1, soo = o0 + o1;
    float dd = m0 - m1;
    t[0] = RA * (see + soo);
    t[4] = RA * (see - soo);
    float p2 = RA * dee;
    t[2] = p2; t[6] = p2;
    float a0 = RA * d0, a1 = RB * dd;
    t[1] = a0 + a1; t[7] = a0 + a1;
    t[3] = a0 - a1; t[5] = a0 - a1;
}

// Full sin butterfly: t[u] = sum_m x[m] sin(2pi um/8)/sqrt8
__device__ __forceinline__ void dft8_sin(const float* __restrict__ x, float* __restrict__ t) {
    float d1 = x[2] - x[6];
    float o0 = x[1] + x[5], m0 = x[1] - x[5];
    float o1 = x[3] + x[7], m1 = x[3] - x[7];
    float qq = m0 + m1;
    t[0] = 0.0f; t[4] = 0.0f;
    float q2 = RA * (o0 - o1);
    t[2] = q2; t[6] = -q2;
    float a0 = RB * qq, a1 = RA * d1;
    t[1] = a0 + a1; t[7] = -(a0 + a1);
    t[3] = a0 - a1; t[5] = -(a0 - a1);
}

__device__ __forceinline__ float nonlin(float t) {
    float ca = fabsf(t);
    t = (ca < 2.5f) ? t * (ca * 0.4f) : t;
    return fminf(fmaxf(t, -10.0f), 10.0f);
}

// In-place packed column transform on A[8][8] (rows = packed RFFT of B rows).
// Writes T[u][v] at A[u][sg(v)] where sg = {0,1,2,3,4,7,6,5}.
template <bool NL>
__device__ __forceinline__ void colpass(float A[8][8]) {
#pragma unroll
    for (int v0 = 0; v0 <= 4; v0 += 4) {   // q-columns are zero here
        float c[8], t[8];
#pragma unroll
        for (int m = 0; m < 8; ++m) c[m] = A[m][v0];
        dft8_cos(c, t);
#pragma unroll
        for (int u = 0; u < 8; ++u) A[u][v0] = NL ? nonlin(t[u]) : t[u];
    }
#pragma unroll
    for (int v = 1; v <= 3; ++v) {         // pair (v, 8-v): cv -+ sv
        float c[8], q[8], tc[8], ts[8];
#pragma unroll
        for (int m = 0; m < 8; ++m) { c[m] = A[m][v]; q[m] = A[m][4 + v]; }
        dft8_cos(c, tc);
        dft8_sin(q, ts);
#pragma unroll
        for (int u = 0; u < 8; ++u) {
            float lo = tc[u] - ts[u];      // T[u][v]
            float hi = tc[u] + ts[u];      // T[u][8-v] -> slot 4+v
            A[u][v] = NL ? nonlin(lo) : lo;
            A[u][4 + v] = NL ? nonlin(hi) : hi;
        }
    }
}

// block=256, 2 waves/EU: live set (B[64]+A[64]+20xfx4 prefetch) needs ~220 VGPR.
// (256,3) made the compiler target ~84 VGPR -> massive scratch spill (R4: WRITE_SIZE
// 383MB vs 197 ideal, VALUBusy 14%, dur 181us). Do NOT raise the occupancy bound.
__launch_bounds__(256, 2)
__global__ void sas_fused(const float* __restrict__ in, float* __restrict__ out) {
    const int lane = threadIdx.x & 63;   // block-col 0..63
    const int wv = threadIdx.x >> 6;
    const int p = blockIdx.y;            // plane (b*3+c)
    const int by = blockIdx.x * 4 + wv;  // block-row 0..63
    const float* __restrict__ inP = in + (size_t)p * (HW * HW);
    const int cx = lane * 8;

    const float e = 0.45783336f;                  // exp(-1/1.28)
    const float inv_s = 1.0f / ((1.0f + 2.0f * e) * (1.0f + 2.0f * e));

    // ---- all 10 halo-row loads issued up front (coalesced full-row reads) ----
    fx4 va[10], vb[10];
#pragma unroll
    for (int j = 0; j < 10; ++j) {
        int gy = reflect512(by * 8 - 1 + j);
        const float* r = inP + (size_t)gy * HW + cx;
        va[j] = *(const fx4*)r;
        vb[j] = *(const fx4*)(r + 4);
    }

    // ---- streaming blur (3-row ring) + row-pass into packed A; keep B for residual ----
    float h[3][8];
    float B[8][8], A[8][8];
#pragma unroll
    for (int j = 0; j < 10; ++j) {
        float lft = __shfl_up(vb[j].w, 1);
        float rgt = __shfl_down(va[j].x, 1);
        if (lane == 0)  lft = va[j].y;
        if (lane == 63) rgt = vb[j].z;
        float x0 = lft, x1 = va[j].x, x2 = va[j].y, x3 = va[j].z, x4 = va[j].w;
        float x5 = vb[j].x, x6 = vb[j].y, x7 = vb[j].z, x8 = vb[j].w, x9 = rgt;
        float* hj = h[j % 3];
        hj[0] = e * (x0 + x2) + x1;
        hj[1] = e * (x1 + x3) + x2;
        hj[2] = e * (x2 + x4) + x3;
        hj[3] = e * (x3 + x5) + x4;
        hj[4] = e * (x4 + x6) + x5;
        hj[5] = e * (x5 + x7) + x6;
        hj[6] = e * (x6 + x8) + x7;
        hj[7] = e * (x7 + x9) + x8;
        if (j >= 2) {
            const int r = j - 2;
            const float* h0 = h[r % 3];
            const float* h1 = h[(r + 1) % 3];
            const float* h2 = h[(r + 2) % 3];
#pragma unroll
            for (int c = 0; c < 8; ++c)
                B[r][c] = (e * (h0[c] + h2[c]) + h1[c]) * inv_s;
            rfft8(B[r], A[r]);
        }
    }

    // ---- forward col pass + nonlinearity (T in A, permuted cols) ----
    colpass<true>(A);

    // ---- inverse: row pass (read with sg permutation), then col pass ----
#pragma unroll
    for (int m = 0; m < 8; ++m) {
        float x[8] = {A[m][0], A[m][1], A[m][2], A[m][3],
                      A[m][4], A[m][7], A[m][6], A[m][5]};
        rfft8(x, A[m]);
    }
    colpass<false>(A);
    // rec[u][v] now at A[u][sg(v)], sg = {0,1,2,3,4,7,6,5}

    // ---- residual + Haar refine + nontemporal coalesced stores ----
    constexpr int SG[8] = {0, 1, 2, 3, 4, 7, 6, 5};
    const int chId = (p / 3) * 6 + (p % 3);
    float* __restrict__ oI = out + ((size_t)chId << 18);
    float* __restrict__ oR = out + ((size_t)(chId + 3) << 18);
#pragma unroll
    for (int qy = 0; qy < 4; ++qy) {
        float ti[2][8], tr_[2][8];
#pragma unroll
        for (int qx = 0; qx < 4; ++qx) {
            float d00 = A[2*qy][SG[2*qx]],   d01 = A[2*qy][SG[2*qx+1]];
            float d10 = A[2*qy+1][SG[2*qx]], d11 = A[2*qy+1][SG[2*qx+1]];
            haar_quad(d00, d01, d10, d11,
                      ti[0][2*qx], ti[0][2*qx+1], ti[1][2*qx], ti[1][2*qx+1]);
            float r00 = B[2*qy][2*qx]   - d00, r01 = B[2*qy][2*qx+1]   - d01;
            float r10 = B[2*qy+1][2*qx] - d10, r11 = B[2*qy+1][2*qx+1] - d11;
            haar_quad(r00, r01, r10, r11,
                      tr_[0][2*qx], tr_[0][2*qx+1], tr_[1][2*qx], tr_[1][2*qx+1]);
        }
        size_t base = (size_t)(by * 8 + 2 * qy) * HW + cx;
        fx4 w;
        w = (fx4){ti[0][0], ti[0][1], ti[0][2], ti[0][3]};
        __builtin_nontemporal_store(w, (fx4*)&oI[base]);
        w = (fx4){ti[0][4], ti[0][5], ti[0][6], ti[0][7]};
        __builtin_nontemporal_store(w, (fx4*)&oI[base + 4]);
        w = (fx4){ti[1][0], ti[1][1], ti[1][2], ti[1][3]};
        __builtin_nontemporal_store(w, (fx4*)&oI[base + HW]);
        w = (fx4){ti[1][4], ti[1][5], ti[1][6], ti[1][7]};
        __builtin_nontemporal_store(w, (fx4*)&oI[base + HW + 4]);
        w = (fx4){tr_[0][0], tr_[0][1], tr_[0][2], tr_[0][3]};
        __builtin_nontemporal_store(w, (fx4*)&oR[base]);
        w = (fx4){tr_[0][4], tr_[0][5], tr_[0][6], tr_[0][7]};
        __builtin_nontemporal_store(w, (fx4*)&oR[base + 4]);
        w = (fx4){tr_[1][0], tr_[1][1], tr_[1][2], tr_[1][3]};
        __builtin_nontemporal_store(w, (fx4*)&oR[base + HW]);
        w = (fx4){tr_[1][4], tr_[1][5], tr_[1][6], tr_[1][7]};
        __builtin_nontemporal_store(w, (fx4*)&oR[base + HW + 4]);
    }
}

extern "C" void kernel_launch(void* const* d_in, const int* in_sizes, int n_in,
                              void* d_out, int out_size, void* d_ws, size_t ws_size,
                              hipStream_t stream) {
    const float* I = (const float*)d_in[0];
    float* out = (float*)d_out;
    dim3 grid(16, 96);   // 16 wg x 4 waves = 64 block-rows per plane; 96 planes
    sas_fused<<<grid, dim3(256), 0, stream>>>(I, out);
}